// Round 3
// baseline (7015.201 us; speedup 1.0000x reference)
//
#include <hip/hip_runtime.h>
#include <hip/hip_bf16.h>
#include <hip/hip_fp16.h>
#include <math.h>

#define B_ 4
#define N_ 2048
#define D_ 512

typedef __bf16    bf16x8  __attribute__((ext_vector_type(8)));
typedef float     floatx4 __attribute__((ext_vector_type(4)));
typedef _Float16  half8   __attribute__((ext_vector_type(8)));

// fast base-2 exp/log (v_exp_f32 / v_log_f32 are natively base-2 on gfx950)
#if __has_builtin(__builtin_amdgcn_exp2f)
__device__ __forceinline__ float fexp2(float x) { return __builtin_amdgcn_exp2f(x); }
#else
__device__ __forceinline__ float fexp2(float x) { return exp2f(x); }
#endif
#if __has_builtin(__builtin_amdgcn_logf)
__device__ __forceinline__ float flog2(float x) { return __builtin_amdgcn_logf(x); }
#else
__device__ __forceinline__ float flog2(float x) { return __log2f(x); }
#endif

// ---------------------------------------------------------------------------
// async global->LDS, 16B per lane, wave-uniform LDS base (HW adds lane*16)
// ---------------------------------------------------------------------------
__device__ __forceinline__ void gload16(const void* g, void* l) {
  __builtin_amdgcn_global_load_lds(
      (const __attribute__((address_space(1))) void*)g,
      (__attribute__((address_space(3))) void*)l, 16, 0, 0);
}

// ---------------------------------------------------------------------------
// L2-normalize rows of (rows, 512) f32 -> bf16
// ---------------------------------------------------------------------------
__global__ __launch_bounds__(256) void norm_kernel(const float* __restrict__ in,
                                                   __hip_bfloat16* __restrict__ out) {
  const size_t row = blockIdx.x;
  const int t = threadIdx.x;
  const float* src = in + row * D_;
  float v0 = src[t], v1 = src[t + 256];
  float ss = fmaf(v0, v0, v1 * v1);
#pragma unroll
  for (int off = 1; off < 64; off <<= 1) ss += __shfl_xor(ss, off);
  __shared__ float red[4];
  if ((t & 63) == 0) red[t >> 6] = ss;
  __syncthreads();
  const float tot = red[0] + red[1] + red[2] + red[3];
  const float scale = 1.0f / fmaxf(sqrtf(tot), 1e-12f);
  out[row * D_ + t]       = __float2bfloat16(v0 * scale);
  out[row * D_ + t + 256] = __float2bfloat16(v1 * scale);
}

// ---------------------------------------------------------------------------
// Batched NT GEMM producing the 3 Gram matrices in one dispatch.
// z: mat = z>>2 (0: X·Yt, 1: X·Xt, 2: Y·Yt), batch = z&3
// ---------------------------------------------------------------------------
__global__ __launch_bounds__(256) void gram_gemm(const __hip_bfloat16* __restrict__ X,
                                                 const __hip_bfloat16* __restrict__ Y,
                                                 __half* __restrict__ Gxy,
                                                 __half* __restrict__ Gxx,
                                                 __half* __restrict__ Gyy) {
  __shared__ __hip_bfloat16 As[128 * 32];
  __shared__ __hip_bfloat16 Bs[128 * 32];
  const int t = threadIdx.x;
  const int wave = t >> 6, lane = t & 63;
  const int bm0 = blockIdx.x * 128, bn0 = blockIdx.y * 128;
  const int mat = blockIdx.z >> 2;
  const size_t bb = blockIdx.z & 3;
  const __hip_bfloat16* Ab = (mat == 2 ? Y : X) + bb * (size_t)(N_ * D_);
  const __hip_bfloat16* Bb = (mat == 1 ? X : Y) + bb * (size_t)(N_ * D_);
  __half* Gb = (mat == 0 ? Gxy : mat == 1 ? Gxx : Gyy) + bb * (size_t)N_ * N_;

  floatx4 acc[4][4] = {};
  const int wr = wave >> 1, wc = wave & 1;
  const int srow = t >> 2;
  const int scol = (t & 3) * 8;
  char* AsB = (char*)As;
  char* BsB = (char*)Bs;
  const int ldsOff = wave * 1024;

  for (int k0 = 0; k0 < D_; k0 += 32) {
    __syncthreads();
    gload16(Ab + (size_t)(bm0 + srow)      * D_ + k0 + scol, AsB + ldsOff);
    gload16(Ab + (size_t)(bm0 + 64 + srow) * D_ + k0 + scol, AsB + 4096 + ldsOff);
    gload16(Bb + (size_t)(bn0 + srow)      * D_ + k0 + scol, BsB + ldsOff);
    gload16(Bb + (size_t)(bn0 + 64 + srow) * D_ + k0 + scol, BsB + 4096 + ldsOff);
    __syncthreads();

    const int lrow = lane & 15, lk = (lane >> 4) * 8;
    bf16x8 af[4], bfr[4];
#pragma unroll
    for (int mi = 0; mi < 4; ++mi)
      af[mi] = *(const bf16x8*)((const char*)As + ((wr * 64 + mi * 16 + lrow) * 32 + lk) * 2);
#pragma unroll
    for (int ni = 0; ni < 4; ++ni)
      bfr[ni] = *(const bf16x8*)((const char*)Bs + ((wc * 64 + ni * 16 + lrow) * 32 + lk) * 2);
#pragma unroll
    for (int mi = 0; mi < 4; ++mi)
#pragma unroll
      for (int ni = 0; ni < 4; ++ni)
        acc[mi][ni] = __builtin_amdgcn_mfma_f32_16x16x32_bf16(af[mi], bfr[ni], acc[mi][ni], 0, 0, 0);
  }

  const int orow = (lane >> 4) * 4, ocol = lane & 15;
#pragma unroll
  for (int mi = 0; mi < 4; ++mi)
#pragma unroll
    for (int ni = 0; ni < 4; ++ni) {
      const int row = bm0 + wr * 64 + mi * 16 + orow;
      const int col = bn0 + wc * 64 + ni * 16 + ocol;
#pragma unroll
      for (int r = 0; r < 4; ++r)
        Gb[(size_t)(row + r) * N_ + col] = __float2half(acc[mi][ni][r]);
    }
}

// ---------------------------------------------------------------------------
// Fused streaming pass. 768 blocks, mat = bid % 3:
//   mat 0 (Gxy): row-LSE -> new f_ba (slot 0); column-LSE partials -> colPart
//   mat 1 (Gxx): row-LSE -> new f_aa (slot 2)
//   mat 2 (Gyy): row-LSE -> new g_bb (slot 3)
// All math in log2 domain. pot layout: [slot][B][N], slot 0 f_ba, 1 g_ab,
// 2 f_aa, 3 g_bb. colPart layout: [b][stripe][idx] float2, idx = p*512+e*64+lane.
// MODE 0: init (h = log_w), direct write. MODE 1: damped 0.5(old+new).
// MODE 2: final, accumulate signed loss terms into *out.
// ---------------------------------------------------------------------------
#define L2E_ 1.44269504088896f
#define LN2_ 0.69314718055995f

template <int MODE>
__global__ __launch_bounds__(256, 3) void sink_stream(
    const __half* __restrict__ Gxy, const __half* __restrict__ Gxx,
    const __half* __restrict__ Gyy,
    const float* __restrict__ potOld, float* __restrict__ potNew,
    float2* __restrict__ colPart, float eps, float* __restrict__ out) {
  __shared__ float cw[3][2048][2];   // cross-wave column-partial merge (48 KB)
  __shared__ float redls[4];

  const int bid = blockIdx.x;
  const int mat = bid % 3;
  const int rem = bid / 3;
  const int b = rem >> 6, stripe = rem & 63;
  const int lane = threadIdx.x & 63, wave = threadIdx.x >> 6;

  const float inv_eps = 1.0f / eps;
  const float ieL  = inv_eps * L2E_;
  const float hbL  = (-7.62461898616f - inv_eps) * L2E_;  // (-log 2048 - 1/eps)*log2e
  const float negEpsLn2 = -eps * LN2_;

  const __half* G = (mat == 0 ? Gxy : mat == 1 ? Gxx : Gyy) + (size_t)b * N_ * N_;
  const int hIdx = (mat == 0) ? 1 : (mat == 1) ? 2 : 3;
  const int oIdx = (mat == 0) ? 0 : hIdx;
  const float* potH = potOld + ((size_t)hIdx * B_ + b) * N_;
  const float* potR = potOld + ((size_t)0    * B_ + b) * N_;  // f_ba (col pass)
  const float* potO = potOld + ((size_t)oIdx * B_ + b) * N_;
  float*       potW = potNew + ((size_t)oIdx * B_ + b) * N_;

  // per-lane h for the 32 owned columns (log2 domain)
  float hh[32];
  if constexpr (MODE == 0) {
#pragma unroll
    for (int j = 0; j < 32; ++j) hh[j] = hbL;
  } else {
#pragma unroll
    for (int p = 0; p < 4; ++p) {
      const float4 a = *(const float4*)(potH + p * 512 + lane * 8);
      const float4 c = *(const float4*)(potH + p * 512 + lane * 8 + 4);
      hh[p * 8 + 0] = fmaf(a.x, ieL, hbL);
      hh[p * 8 + 1] = fmaf(a.y, ieL, hbL);
      hh[p * 8 + 2] = fmaf(a.z, ieL, hbL);
      hh[p * 8 + 3] = fmaf(a.w, ieL, hbL);
      hh[p * 8 + 4] = fmaf(c.x, ieL, hbL);
      hh[p * 8 + 5] = fmaf(c.y, ieL, hbL);
      hh[p * 8 + 6] = fmaf(c.z, ieL, hbL);
      hh[p * 8 + 7] = fmaf(c.w, ieL, hbL);
    }
  }

  // online column accumulators (xy blocks only)
  float colm[32], cols_[32];
#pragma unroll
  for (int j = 0; j < 32; ++j) { colm[j] = -3.0e38f; cols_[j] = 0.0f; }

  float lsum = 0.0f;

  const int rbase = stripe * 32 + wave * 8;
  half8 A0[4], A1[4], P0[4], P1[4];
  {
    const __half* gp0 = G + (size_t)rbase * N_ + lane * 8;
#pragma unroll
    for (int p = 0; p < 4; ++p) {
      A0[p] = *(const half8*)(gp0 + p * 512);
      A1[p] = *(const half8*)(gp0 + N_ + p * 512);
    }
  }

#pragma unroll 1
  for (int it = 0; it < 4; ++it) {
    const int r0 = rbase + it * 2;
    if (it < 3) {  // prefetch next row pair
      const __half* gp = G + (size_t)(r0 + 2) * N_ + lane * 8;
#pragma unroll
      for (int p = 0; p < 4; ++p) {
        P0[p] = *(const half8*)(gp + p * 512);
        P1[p] = *(const half8*)(gp + N_ + p * 512);
      }
    }

    float hr0 = hbL, hr1 = hbL;
    if (mat == 0 && MODE != 0) {
      hr0 = fmaf(potR[r0],     ieL, hbL);
      hr1 = fmaf(potR[r0 + 1], ieL, hbL);
    }

    // pass 1: row max (log2 domain)
    float mx0 = -3.0e38f, mx1 = -3.0e38f;
#pragma unroll
    for (int p = 0; p < 4; ++p)
#pragma unroll
      for (int e = 0; e < 8; ++e) {
        const int j = p * 8 + e;
        mx0 = fmaxf(mx0, fmaf((float)A0[p][e], ieL, hh[j]));
        mx1 = fmaxf(mx1, fmaf((float)A1[p][e], ieL, hh[j]));
      }
#pragma unroll
    for (int off = 1; off < 64; off <<= 1) {
      mx0 = fmaxf(mx0, __shfl_xor(mx0, off));
      mx1 = fmaxf(mx1, __shfl_xor(mx1, off));
    }

    // pass 2: row exp2-sum; fused online column update (both rows at once)
    float sm0 = 0.0f, sm1 = 0.0f;
#pragma unroll
    for (int p = 0; p < 4; ++p)
#pragma unroll
      for (int e = 0; e < 8; ++e) {
        const int j = p * 8 + e;
        const float u0 = (float)A0[p][e] * ieL;
        const float u1 = (float)A1[p][e] * ieL;
        sm0 += fexp2(u0 + hh[j] - mx0);
        sm1 += fexp2(u1 + hh[j] - mx1);
        if (mat == 0) {
          const float t0 = u0 + hr0, t1 = u1 + hr1;
          const float nm = fmaxf(colm[j], fmaxf(t0, t1));
          const float add = fexp2(t0 - nm) + fexp2(t1 - nm);
          cols_[j] = fmaf(cols_[j], fexp2(colm[j] - nm), add);
          colm[j] = nm;
        }
      }
#pragma unroll
    for (int off = 1; off < 64; off <<= 1) {
      sm0 += __shfl_xor(sm0, off);
      sm1 += __shfl_xor(sm1, off);
    }

    const float v0 = negEpsLn2 * (mx0 + flog2(sm0));
    const float v1 = negEpsLn2 * (mx1 + flog2(sm1));

    if constexpr (MODE == 2) {
      if (lane == 0) lsum += v0 + v1;
    } else if constexpr (MODE == 1) {
      if (lane == 0) {
        potW[r0]     = 0.5f * (potO[r0]     + v0);
        potW[r0 + 1] = 0.5f * (potO[r0 + 1] + v1);
      }
    } else {
      if (lane == 0) {
        potW[r0]     = v0;
        potW[r0 + 1] = v1;
      }
    }

    // rotate prefetch
#pragma unroll
    for (int p = 0; p < 4; ++p) { A0[p] = P0[p]; A1[p] = P1[p]; }
  }

  // --- xy blocks: merge column partials across waves, write to global ---
  if (mat == 0) {
    if (wave != 0) {
#pragma unroll
      for (int j = 0; j < 32; ++j) {
        const int idx = (j >> 3) * 512 + (j & 7) * 64 + lane;
        cw[wave - 1][idx][0] = colm[j];
        cw[wave - 1][idx][1] = cols_[j];
      }
    }
    __syncthreads();
    if (wave == 0) {
#pragma unroll
      for (int w = 0; w < 3; ++w)
#pragma unroll
        for (int j = 0; j < 32; ++j) {
          const int idx = (j >> 3) * 512 + (j & 7) * 64 + lane;
          const float m2 = cw[w][idx][0], s2 = cw[w][idx][1];
          const float nm = fmaxf(colm[j], m2);
          cols_[j] = fmaf(cols_[j], fexp2(colm[j] - nm), s2 * fexp2(m2 - nm));
          colm[j] = nm;
        }
      float2* cp = colPart + ((size_t)(b * 64 + stripe)) * 2048;
#pragma unroll
      for (int j = 0; j < 32; ++j) {
        const int idx = (j >> 3) * 512 + (j & 7) * 64 + lane;
        cp[idx] = make_float2(colm[j], cols_[j]);
      }
    }
  }

  if constexpr (MODE == 2) {
    if (lane == 0) redls[wave] = lsum;
    __syncthreads();
    if (threadIdx.x == 0) {
      const float sign = (mat == 0) ? 1.0f : -1.0f;
      atomicAdd(out, sign * (redls[0] + redls[1] + redls[2] + redls[3]) *
                         (1.0f / (2048.0f * B_)));
    }
  }
}

// ---------------------------------------------------------------------------
// Merge column partials across the 64 row-stripes -> g_ab update (slot 1).
// 32 blocks x 256 threads; thread handles one permuted column idx.
// ---------------------------------------------------------------------------
template <int MODE>
__global__ __launch_bounds__(256) void sink_merge(
    const float2* __restrict__ colPart, const float* __restrict__ potOld,
    float* __restrict__ potNew, float eps, float* __restrict__ out) {
  const int gid = blockIdx.x * 256 + threadIdx.x;   // 0..8191
  const int b = gid >> 11, idx = gid & 2047;
  const float negEpsLn2 = -eps * LN2_;

  float m = -3.0e38f, s = 0.0f;
  const float2* cp = colPart + (size_t)b * 64 * 2048 + idx;
#pragma unroll 8
  for (int st = 0; st < 64; ++st) {
    const float2 P = cp[(size_t)st * 2048];
    const float nm = fmaxf(m, P.x);
    s = fmaf(s, fexp2(m - nm), P.y * fexp2(P.x - nm));
    m = nm;
  }
  const float v = negEpsLn2 * (m + flog2(s));

  // decode permuted idx -> column
  const int p = idx >> 9, e = (idx >> 6) & 7, l = idx & 63;
  const int col = p * 512 + l * 8 + e;

  if constexpr (MODE == 0) {
    potNew[((size_t)1 * B_ + b) * N_ + col] = v;
  } else if constexpr (MODE == 1) {
    potNew[((size_t)1 * B_ + b) * N_ + col] =
        0.5f * (potOld[((size_t)1 * B_ + b) * N_ + col] + v);
  } else {
    float acc = v;
#pragma unroll
    for (int off = 1; off < 64; off <<= 1) acc += __shfl_xor(acc, off);
    __shared__ float red[4];
    if ((threadIdx.x & 63) == 0) red[threadIdx.x >> 6] = acc;
    __syncthreads();
    if (threadIdx.x == 0)
      atomicAdd(out, (red[0] + red[1] + red[2] + red[3]) * (1.0f / (2048.0f * B_)));
  }
}

// ---------------------------------------------------------------------------
extern "C" void kernel_launch(void* const* d_in, const int* in_sizes, int n_in,
                              void* d_out, int out_size, void* d_ws, size_t ws_size,
                              hipStream_t stream) {
  const float* E_p = (const float*)d_in[0];
  const float* E_t = (const float*)d_in[1];
  float* out = (float*)d_out;
  char* ws = (char*)d_ws;

  size_t off = 0;
  auto alloc = [&](size_t bytes) {
    void* p = ws + off;
    off += (bytes + 255) & ~(size_t)255;
    return p;
  };
  __hip_bfloat16* Xb = (__hip_bfloat16*)alloc((size_t)B_ * N_ * D_ * 2);
  __hip_bfloat16* Yb = (__hip_bfloat16*)alloc((size_t)B_ * N_ * D_ * 2);
  __half* Gxy = (__half*)alloc((size_t)B_ * N_ * N_ * 2);
  __half* Gxx = (__half*)alloc((size_t)B_ * N_ * N_ * 2);
  __half* Gyy = (__half*)alloc((size_t)B_ * N_ * N_ * 2);
  float* potA = (float*)alloc((size_t)4 * B_ * N_ * 4);
  float* potB = (float*)alloc((size_t)4 * B_ * N_ * 4);
  float2* colPart = (float2*)alloc((size_t)B_ * 64 * 2048 * 8);

  norm_kernel<<<B_ * N_, 256, 0, stream>>>(E_p, Xb);
  norm_kernel<<<B_ * N_, 256, 0, stream>>>(E_t, Yb);

  dim3 gg(16, 16, 12);
  gram_gemm<<<gg, 256, 0, stream>>>(Xb, Yb, Gxy, Gxx, Gyy);

  // epsilon schedule (numpy arange semantics, double precision)
  float epsl[48];
  int ne = 0;
  epsl[ne++] = 4.0f;
  {
    const double lstart = 2.0 * log(2.0);
    const double lstop  = 2.0 * log(0.05);
    const double lstep  = 2.0 * log(0.9);
    for (int k = 0;; ++k) {
      const double v = lstart + k * lstep;
      if (!(v > lstop)) break;
      epsl[ne++] = (float)exp(v);
    }
  }
  epsl[ne++] = 0.0025f;

  // init at eps0
  sink_stream<0><<<768, 256, 0, stream>>>(Gxy, Gxx, Gyy, potA, potA, colPart,
                                          epsl[0], nullptr);
  sink_merge<0><<<32, 256, 0, stream>>>(colPart, potA, potA, epsl[0], nullptr);

  // damped scan over the schedule
  float* cur = potA;
  float* nxt = potB;
  for (int i = 0; i < ne; ++i) {
    sink_stream<1><<<768, 256, 0, stream>>>(Gxy, Gxx, Gyy, cur, nxt, colPart,
                                            epsl[i], nullptr);
    sink_merge<1><<<32, 256, 0, stream>>>(colPart, cur, nxt, epsl[i], nullptr);
    float* tmp = cur; cur = nxt; nxt = tmp;
  }

  // final extrapolation + loss
  (void)hipMemsetAsync(d_out, 0, sizeof(float), stream);
  sink_stream<2><<<768, 256, 0, stream>>>(Gxy, Gxx, Gyy, cur, cur, colPart,
                                          epsl[ne - 1], out);
  sink_merge<2><<<32, 256, 0, stream>>>(colPart, cur, cur, epsl[ne - 1], out);
}

// Round 4
// 1859.450 us; speedup vs baseline: 3.7727x; 3.7727x over previous
//
#include <hip/hip_runtime.h>
#include <hip/hip_bf16.h>
#include <hip/hip_fp16.h>
#include <math.h>

#define B_ 4
#define N_ 2048
#define D_ 512

typedef __bf16    bf16x8  __attribute__((ext_vector_type(8)));
typedef float     floatx4 __attribute__((ext_vector_type(4)));
typedef _Float16  half8   __attribute__((ext_vector_type(8)));

// fast base-2 exp/log (v_exp_f32 / v_log_f32 are natively base-2 on gfx950)
#if __has_builtin(__builtin_amdgcn_exp2f)
__device__ __forceinline__ float fexp2(float x) { return __builtin_amdgcn_exp2f(x); }
#else
__device__ __forceinline__ float fexp2(float x) { return exp2f(x); }
#endif
#if __has_builtin(__builtin_amdgcn_logf)
__device__ __forceinline__ float flog2(float x) { return __builtin_amdgcn_logf(x); }
#else
__device__ __forceinline__ float flog2(float x) { return __log2f(x); }
#endif

// ---------------------------------------------------------------------------
// async global->LDS, 16B per lane, wave-uniform LDS base (HW adds lane*16)
// ---------------------------------------------------------------------------
__device__ __forceinline__ void gload16(const void* g, void* l) {
  __builtin_amdgcn_global_load_lds(
      (const __attribute__((address_space(1))) void*)g,
      (__attribute__((address_space(3))) void*)l, 16, 0, 0);
}

// ---------------------------------------------------------------------------
// L2-normalize rows of (rows, 512) f32 -> bf16
// ---------------------------------------------------------------------------
__global__ __launch_bounds__(256) void norm_kernel(const float* __restrict__ in,
                                                   __hip_bfloat16* __restrict__ out) {
  const size_t row = blockIdx.x;
  const int t = threadIdx.x;
  const float* src = in + row * D_;
  float v0 = src[t], v1 = src[t + 256];
  float ss = fmaf(v0, v0, v1 * v1);
#pragma unroll
  for (int off = 1; off < 64; off <<= 1) ss += __shfl_xor(ss, off);
  __shared__ float red[4];
  if ((t & 63) == 0) red[t >> 6] = ss;
  __syncthreads();
  const float tot = red[0] + red[1] + red[2] + red[3];
  const float scale = 1.0f / fmaxf(sqrtf(tot), 1e-12f);
  out[row * D_ + t]       = __float2bfloat16(v0 * scale);
  out[row * D_ + t + 256] = __float2bfloat16(v1 * scale);
}

// ---------------------------------------------------------------------------
// Batched NT GEMM producing the 3 Gram matrices in one dispatch.
// z: mat = z>>2 (0: X·Yt, 1: X·Xt, 2: Y·Yt), batch = z&3
// ---------------------------------------------------------------------------
__global__ __launch_bounds__(256) void gram_gemm(const __hip_bfloat16* __restrict__ X,
                                                 const __hip_bfloat16* __restrict__ Y,
                                                 __half* __restrict__ Gxy,
                                                 __half* __restrict__ Gxx,
                                                 __half* __restrict__ Gyy) {
  __shared__ __hip_bfloat16 As[128 * 32];
  __shared__ __hip_bfloat16 Bs[128 * 32];
  const int t = threadIdx.x;
  const int wave = t >> 6, lane = t & 63;
  const int bm0 = blockIdx.x * 128, bn0 = blockIdx.y * 128;
  const int mat = blockIdx.z >> 2;
  const size_t bb = blockIdx.z & 3;
  const __hip_bfloat16* Ab = (mat == 2 ? Y : X) + bb * (size_t)(N_ * D_);
  const __hip_bfloat16* Bb = (mat == 1 ? X : Y) + bb * (size_t)(N_ * D_);
  __half* Gb = (mat == 0 ? Gxy : mat == 1 ? Gxx : Gyy) + bb * (size_t)N_ * N_;

  floatx4 acc[4][4] = {};
  const int wr = wave >> 1, wc = wave & 1;
  const int srow = t >> 2;
  const int scol = (t & 3) * 8;
  char* AsB = (char*)As;
  char* BsB = (char*)Bs;
  const int ldsOff = wave * 1024;

  for (int k0 = 0; k0 < D_; k0 += 32) {
    __syncthreads();
    gload16(Ab + (size_t)(bm0 + srow)      * D_ + k0 + scol, AsB + ldsOff);
    gload16(Ab + (size_t)(bm0 + 64 + srow) * D_ + k0 + scol, AsB + 4096 + ldsOff);
    gload16(Bb + (size_t)(bn0 + srow)      * D_ + k0 + scol, BsB + ldsOff);
    gload16(Bb + (size_t)(bn0 + 64 + srow) * D_ + k0 + scol, BsB + 4096 + ldsOff);
    __syncthreads();

    const int lrow = lane & 15, lk = (lane >> 4) * 8;
    bf16x8 af[4], bfr[4];
#pragma unroll
    for (int mi = 0; mi < 4; ++mi)
      af[mi] = *(const bf16x8*)((const char*)As + ((wr * 64 + mi * 16 + lrow) * 32 + lk) * 2);
#pragma unroll
    for (int ni = 0; ni < 4; ++ni)
      bfr[ni] = *(const bf16x8*)((const char*)Bs + ((wc * 64 + ni * 16 + lrow) * 32 + lk) * 2);
#pragma unroll
    for (int mi = 0; mi < 4; ++mi)
#pragma unroll
      for (int ni = 0; ni < 4; ++ni)
        acc[mi][ni] = __builtin_amdgcn_mfma_f32_16x16x32_bf16(af[mi], bfr[ni], acc[mi][ni], 0, 0, 0);
  }

  const int orow = (lane >> 4) * 4, ocol = lane & 15;
#pragma unroll
  for (int mi = 0; mi < 4; ++mi)
#pragma unroll
    for (int ni = 0; ni < 4; ++ni) {
      const int row = bm0 + wr * 64 + mi * 16 + orow;
      const int col = bn0 + wc * 64 + ni * 16 + ocol;
#pragma unroll
      for (int r = 0; r < 4; ++r)
        Gb[(size_t)(row + r) * N_ + col] = __float2half(acc[mi][ni][r]);
    }
}

// ---------------------------------------------------------------------------
// Fused streaming pass. 768 blocks, mat = bid % 3:
//   mat 0 (Gxy): row-LSE -> new f_ba (slot 0); column-LSE partials -> colPart
//   mat 1 (Gxx): row-LSE -> new f_aa (slot 2)
//   mat 2 (Gyy): row-LSE -> new g_bb (slot 3)
// All math in log2 domain. pot layout: [slot][B][N], slot 0 f_ba, 1 g_ab,
// 2 f_aa, 3 g_bb. colPart layout: [b][stripe][idx] float2, idx = p*512+e*64+lane.
// MODE 0: init (h = log_w), direct write. MODE 1: damped 0.5(old+new).
// MODE 2: final, accumulate signed loss terms into *out.
// NOTE: launch_bounds min-waves arg must stay at 2 — at 3 the allocator caps
// VGPRs at ~170 and spills ~200 live registers to scratch (R3: 1.9 GB/pass
// scratch writes, 6.5x regression).
// ---------------------------------------------------------------------------
#define L2E_ 1.44269504088896f
#define LN2_ 0.69314718055995f

template <int MODE>
__global__ __launch_bounds__(256, 2) void sink_stream(
    const __half* __restrict__ Gxy, const __half* __restrict__ Gxx,
    const __half* __restrict__ Gyy,
    const float* __restrict__ potOld, float* __restrict__ potNew,
    float2* __restrict__ colPart, float eps, float* __restrict__ out) {
  __shared__ float cw[3][2048][2];   // cross-wave column-partial merge (48 KB)
  __shared__ float redls[4];

  const int bid = blockIdx.x;
  const int mat = bid % 3;
  const int rem = bid / 3;
  const int b = rem >> 6, stripe = rem & 63;
  const int lane = threadIdx.x & 63, wave = threadIdx.x >> 6;

  const float inv_eps = 1.0f / eps;
  const float ieL  = inv_eps * L2E_;
  const float hbL  = (-7.62461898616f - inv_eps) * L2E_;  // (-log 2048 - 1/eps)*log2e
  const float negEpsLn2 = -eps * LN2_;

  const __half* G = (mat == 0 ? Gxy : mat == 1 ? Gxx : Gyy) + (size_t)b * N_ * N_;
  const int hIdx = (mat == 0) ? 1 : (mat == 1) ? 2 : 3;
  const int oIdx = (mat == 0) ? 0 : hIdx;
  const float* potH = potOld + ((size_t)hIdx * B_ + b) * N_;
  const float* potR = potOld + ((size_t)0    * B_ + b) * N_;  // f_ba (col pass)
  const float* potO = potOld + ((size_t)oIdx * B_ + b) * N_;
  float*       potW = potNew + ((size_t)oIdx * B_ + b) * N_;

  // per-lane h for the 32 owned columns (log2 domain)
  float hh[32];
  if constexpr (MODE == 0) {
#pragma unroll
    for (int j = 0; j < 32; ++j) hh[j] = hbL;
  } else {
#pragma unroll
    for (int p = 0; p < 4; ++p) {
      const float4 a = *(const float4*)(potH + p * 512 + lane * 8);
      const float4 c = *(const float4*)(potH + p * 512 + lane * 8 + 4);
      hh[p * 8 + 0] = fmaf(a.x, ieL, hbL);
      hh[p * 8 + 1] = fmaf(a.y, ieL, hbL);
      hh[p * 8 + 2] = fmaf(a.z, ieL, hbL);
      hh[p * 8 + 3] = fmaf(a.w, ieL, hbL);
      hh[p * 8 + 4] = fmaf(c.x, ieL, hbL);
      hh[p * 8 + 5] = fmaf(c.y, ieL, hbL);
      hh[p * 8 + 6] = fmaf(c.z, ieL, hbL);
      hh[p * 8 + 7] = fmaf(c.w, ieL, hbL);
    }
  }

  // online column accumulators (xy blocks only)
  float colm[32], cols_[32];
#pragma unroll
  for (int j = 0; j < 32; ++j) { colm[j] = -3.0e38f; cols_[j] = 0.0f; }

  float lsum = 0.0f;

  const int rbase = stripe * 32 + wave * 8;
  half8 A0[4], A1[4], P0[4], P1[4];
  {
    const __half* gp0 = G + (size_t)rbase * N_ + lane * 8;
#pragma unroll
    for (int p = 0; p < 4; ++p) {
      A0[p] = *(const half8*)(gp0 + p * 512);
      A1[p] = *(const half8*)(gp0 + N_ + p * 512);
    }
  }

#pragma unroll 1
  for (int it = 0; it < 4; ++it) {
    const int r0 = rbase + it * 2;
    if (it < 3) {  // prefetch next row pair
      const __half* gp = G + (size_t)(r0 + 2) * N_ + lane * 8;
#pragma unroll
      for (int p = 0; p < 4; ++p) {
        P0[p] = *(const half8*)(gp + p * 512);
        P1[p] = *(const half8*)(gp + N_ + p * 512);
      }
    }

    float hr0 = hbL, hr1 = hbL;
    if (mat == 0 && MODE != 0) {
      hr0 = fmaf(potR[r0],     ieL, hbL);
      hr1 = fmaf(potR[r0 + 1], ieL, hbL);
    }

    // pass 1: row max (log2 domain)
    float mx0 = -3.0e38f, mx1 = -3.0e38f;
#pragma unroll
    for (int p = 0; p < 4; ++p)
#pragma unroll
      for (int e = 0; e < 8; ++e) {
        const int j = p * 8 + e;
        mx0 = fmaxf(mx0, fmaf((float)A0[p][e], ieL, hh[j]));
        mx1 = fmaxf(mx1, fmaf((float)A1[p][e], ieL, hh[j]));
      }
#pragma unroll
    for (int off = 1; off < 64; off <<= 1) {
      mx0 = fmaxf(mx0, __shfl_xor(mx0, off));
      mx1 = fmaxf(mx1, __shfl_xor(mx1, off));
    }

    // pass 2: row exp2-sum; fused online column update (both rows at once)
    float sm0 = 0.0f, sm1 = 0.0f;
#pragma unroll
    for (int p = 0; p < 4; ++p)
#pragma unroll
      for (int e = 0; e < 8; ++e) {
        const int j = p * 8 + e;
        const float u0 = (float)A0[p][e] * ieL;
        const float u1 = (float)A1[p][e] * ieL;
        sm0 += fexp2(u0 + hh[j] - mx0);
        sm1 += fexp2(u1 + hh[j] - mx1);
        if (mat == 0) {
          const float t0 = u0 + hr0, t1 = u1 + hr1;
          const float nm = fmaxf(colm[j], fmaxf(t0, t1));
          const float add = fexp2(t0 - nm) + fexp2(t1 - nm);
          cols_[j] = fmaf(cols_[j], fexp2(colm[j] - nm), add);
          colm[j] = nm;
        }
      }
#pragma unroll
    for (int off = 1; off < 64; off <<= 1) {
      sm0 += __shfl_xor(sm0, off);
      sm1 += __shfl_xor(sm1, off);
    }

    const float v0 = negEpsLn2 * (mx0 + flog2(sm0));
    const float v1 = negEpsLn2 * (mx1 + flog2(sm1));

    if constexpr (MODE == 2) {
      if (lane == 0) lsum += v0 + v1;
    } else if constexpr (MODE == 1) {
      if (lane == 0) {
        potW[r0]     = 0.5f * (potO[r0]     + v0);
        potW[r0 + 1] = 0.5f * (potO[r0 + 1] + v1);
      }
    } else {
      if (lane == 0) {
        potW[r0]     = v0;
        potW[r0 + 1] = v1;
      }
    }

    // rotate prefetch
#pragma unroll
    for (int p = 0; p < 4; ++p) { A0[p] = P0[p]; A1[p] = P1[p]; }
  }

  // --- xy blocks: merge column partials across waves, write to global ---
  if (mat == 0) {
    if (wave != 0) {
#pragma unroll
      for (int j = 0; j < 32; ++j) {
        const int idx = (j >> 3) * 512 + (j & 7) * 64 + lane;
        cw[wave - 1][idx][0] = colm[j];
        cw[wave - 1][idx][1] = cols_[j];
      }
    }
    __syncthreads();
    if (wave == 0) {
#pragma unroll
      for (int w = 0; w < 3; ++w)
#pragma unroll
        for (int j = 0; j < 32; ++j) {
          const int idx = (j >> 3) * 512 + (j & 7) * 64 + lane;
          const float m2 = cw[w][idx][0], s2 = cw[w][idx][1];
          const float nm = fmaxf(colm[j], m2);
          cols_[j] = fmaf(cols_[j], fexp2(colm[j] - nm), s2 * fexp2(m2 - nm));
          colm[j] = nm;
        }
      float2* cp = colPart + ((size_t)(b * 64 + stripe)) * 2048;
#pragma unroll
      for (int j = 0; j < 32; ++j) {
        const int idx = (j >> 3) * 512 + (j & 7) * 64 + lane;
        cp[idx] = make_float2(colm[j], cols_[j]);
      }
    }
  }

  if constexpr (MODE == 2) {
    if (lane == 0) redls[wave] = lsum;
    __syncthreads();
    if (threadIdx.x == 0) {
      const float sign = (mat == 0) ? 1.0f : -1.0f;
      atomicAdd(out, sign * (redls[0] + redls[1] + redls[2] + redls[3]) *
                         (1.0f / (2048.0f * B_)));
    }
  }
}

// ---------------------------------------------------------------------------
// Merge column partials across the 64 row-stripes -> g_ab update (slot 1).
// 32 blocks x 256 threads; thread handles one permuted column idx.
// ---------------------------------------------------------------------------
template <int MODE>
__global__ __launch_bounds__(256) void sink_merge(
    const float2* __restrict__ colPart, const float* __restrict__ potOld,
    float* __restrict__ potNew, float eps, float* __restrict__ out) {
  const int gid = blockIdx.x * 256 + threadIdx.x;   // 0..8191
  const int b = gid >> 11, idx = gid & 2047;
  const float negEpsLn2 = -eps * LN2_;

  float m = -3.0e38f, s = 0.0f;
  const float2* cp = colPart + (size_t)b * 64 * 2048 + idx;
#pragma unroll 8
  for (int st = 0; st < 64; ++st) {
    const float2 P = cp[(size_t)st * 2048];
    const float nm = fmaxf(m, P.x);
    s = fmaf(s, fexp2(m - nm), P.y * fexp2(P.x - nm));
    m = nm;
  }
  const float v = negEpsLn2 * (m + flog2(s));

  // decode permuted idx -> column
  const int p = idx >> 9, e = (idx >> 6) & 7, l = idx & 63;
  const int col = p * 512 + l * 8 + e;

  if constexpr (MODE == 0) {
    potNew[((size_t)1 * B_ + b) * N_ + col] = v;
  } else if constexpr (MODE == 1) {
    potNew[((size_t)1 * B_ + b) * N_ + col] =
        0.5f * (potOld[((size_t)1 * B_ + b) * N_ + col] + v);
  } else {
    float acc = v;
#pragma unroll
    for (int off = 1; off < 64; off <<= 1) acc += __shfl_xor(acc, off);
    __shared__ float red[4];
    if ((threadIdx.x & 63) == 0) red[threadIdx.x >> 6] = acc;
    __syncthreads();
    if (threadIdx.x == 0)
      atomicAdd(out, (red[0] + red[1] + red[2] + red[3]) * (1.0f / (2048.0f * B_)));
  }
}

// ---------------------------------------------------------------------------
extern "C" void kernel_launch(void* const* d_in, const int* in_sizes, int n_in,
                              void* d_out, int out_size, void* d_ws, size_t ws_size,
                              hipStream_t stream) {
  const float* E_p = (const float*)d_in[0];
  const float* E_t = (const float*)d_in[1];
  float* out = (float*)d_out;
  char* ws = (char*)d_ws;

  size_t off = 0;
  auto alloc = [&](size_t bytes) {
    void* p = ws + off;
    off += (bytes + 255) & ~(size_t)255;
    return p;
  };
  __hip_bfloat16* Xb = (__hip_bfloat16*)alloc((size_t)B_ * N_ * D_ * 2);
  __hip_bfloat16* Yb = (__hip_bfloat16*)alloc((size_t)B_ * N_ * D_ * 2);
  __half* Gxy = (__half*)alloc((size_t)B_ * N_ * N_ * 2);
  __half* Gxx = (__half*)alloc((size_t)B_ * N_ * N_ * 2);
  __half* Gyy = (__half*)alloc((size_t)B_ * N_ * N_ * 2);
  float* potA = (float*)alloc((size_t)4 * B_ * N_ * 4);
  float* potB = (float*)alloc((size_t)4 * B_ * N_ * 4);
  float2* colPart = (float2*)alloc((size_t)B_ * 64 * 2048 * 8);

  norm_kernel<<<B_ * N_, 256, 0, stream>>>(E_p, Xb);
  norm_kernel<<<B_ * N_, 256, 0, stream>>>(E_t, Yb);

  dim3 gg(16, 16, 12);
  gram_gemm<<<gg, 256, 0, stream>>>(Xb, Yb, Gxy, Gxx, Gyy);

  // epsilon schedule (numpy arange semantics, double precision)
  float epsl[48];
  int ne = 0;
  epsl[ne++] = 4.0f;
  {
    const double lstart = 2.0 * log(2.0);
    const double lstop  = 2.0 * log(0.05);
    const double lstep  = 2.0 * log(0.9);
    for (int k = 0;; ++k) {
      const double v = lstart + k * lstep;
      if (!(v > lstop)) break;
      epsl[ne++] = (float)exp(v);
    }
  }
  epsl[ne++] = 0.0025f;

  // init at eps0
  sink_stream<0><<<768, 256, 0, stream>>>(Gxy, Gxx, Gyy, potA, potA, colPart,
                                          epsl[0], nullptr);
  sink_merge<0><<<32, 256, 0, stream>>>(colPart, potA, potA, epsl[0], nullptr);

  // damped scan over the schedule
  float* cur = potA;
  float* nxt = potB;
  for (int i = 0; i < ne; ++i) {
    sink_stream<1><<<768, 256, 0, stream>>>(Gxy, Gxx, Gyy, cur, nxt, colPart,
                                            epsl[i], nullptr);
    sink_merge<1><<<32, 256, 0, stream>>>(colPart, cur, nxt, epsl[i], nullptr);
    float* tmp = cur; cur = nxt; nxt = tmp;
  }

  // final extrapolation + loss
  (void)hipMemsetAsync(d_out, 0, sizeof(float), stream);
  sink_stream<2><<<768, 256, 0, stream>>>(Gxy, Gxx, Gyy, cur, cur, colPart,
                                          epsl[ne - 1], out);
  sink_merge<2><<<32, 256, 0, stream>>>(colPart, cur, cur, epsl[ne - 1], out);
}

// Round 5
// 1272.977 us; speedup vs baseline: 5.5109x; 1.4607x over previous
//
#include <hip/hip_runtime.h>
#include <hip/hip_bf16.h>
#include <hip/hip_fp16.h>
#include <math.h>

#define B_ 4
#define N_ 2048
#define D_ 512

typedef __bf16    bf16x8  __attribute__((ext_vector_type(8)));
typedef float     floatx4 __attribute__((ext_vector_type(4)));
typedef _Float16  half8   __attribute__((ext_vector_type(8)));

// fast base-2 exp/log (v_exp_f32 / v_log_f32 are natively base-2 on gfx950)
#if __has_builtin(__builtin_amdgcn_exp2f)
__device__ __forceinline__ float fexp2(float x) { return __builtin_amdgcn_exp2f(x); }
#else
__device__ __forceinline__ float fexp2(float x) { return exp2f(x); }
#endif
#if __has_builtin(__builtin_amdgcn_logf)
__device__ __forceinline__ float flog2(float x) { return __builtin_amdgcn_logf(x); }
#else
__device__ __forceinline__ float flog2(float x) { return __log2f(x); }
#endif

// ---------------------------------------------------------------------------
// async global->LDS, 16B per lane, wave-uniform LDS base (HW adds lane*16)
// ---------------------------------------------------------------------------
__device__ __forceinline__ void gload16(const void* g, void* l) {
  __builtin_amdgcn_global_load_lds(
      (const __attribute__((address_space(1))) void*)g,
      (__attribute__((address_space(3))) void*)l, 16, 0, 0);
}

// ---------------------------------------------------------------------------
// L2-normalize rows of (rows, 512) f32 -> bf16
// ---------------------------------------------------------------------------
__global__ __launch_bounds__(256) void norm_kernel(const float* __restrict__ in,
                                                   __hip_bfloat16* __restrict__ out) {
  const size_t row = blockIdx.x;
  const int t = threadIdx.x;
  const float* src = in + row * D_;
  float v0 = src[t], v1 = src[t + 256];
  float ss = fmaf(v0, v0, v1 * v1);
#pragma unroll
  for (int off = 1; off < 64; off <<= 1) ss += __shfl_xor(ss, off);
  __shared__ float red[4];
  if ((t & 63) == 0) red[t >> 6] = ss;
  __syncthreads();
  const float tot = red[0] + red[1] + red[2] + red[3];
  const float scale = 1.0f / fmaxf(sqrtf(tot), 1e-12f);
  out[row * D_ + t]       = __float2bfloat16(v0 * scale);
  out[row * D_ + t + 256] = __float2bfloat16(v1 * scale);
}

// ---------------------------------------------------------------------------
// Batched NT GEMM producing the 3 Gram matrices in one dispatch.
// z: mat = z>>2 (0: X·Yt, 1: X·Xt, 2: Y·Yt), batch = z&3
// ---------------------------------------------------------------------------
__global__ __launch_bounds__(256) void gram_gemm(const __hip_bfloat16* __restrict__ X,
                                                 const __hip_bfloat16* __restrict__ Y,
                                                 __half* __restrict__ Gxy,
                                                 __half* __restrict__ Gxx,
                                                 __half* __restrict__ Gyy) {
  __shared__ __hip_bfloat16 As[128 * 32];
  __shared__ __hip_bfloat16 Bs[128 * 32];
  const int t = threadIdx.x;
  const int wave = t >> 6, lane = t & 63;
  const int bm0 = blockIdx.x * 128, bn0 = blockIdx.y * 128;
  const int mat = blockIdx.z >> 2;
  const size_t bb = blockIdx.z & 3;
  const __hip_bfloat16* Ab = (mat == 2 ? Y : X) + bb * (size_t)(N_ * D_);
  const __hip_bfloat16* Bb = (mat == 1 ? X : Y) + bb * (size_t)(N_ * D_);
  __half* Gb = (mat == 0 ? Gxy : mat == 1 ? Gxx : Gyy) + bb * (size_t)N_ * N_;

  floatx4 acc[4][4] = {};
  const int wr = wave >> 1, wc = wave & 1;
  const int srow = t >> 2;
  const int scol = (t & 3) * 8;
  char* AsB = (char*)As;
  char* BsB = (char*)Bs;
  const int ldsOff = wave * 1024;

  for (int k0 = 0; k0 < D_; k0 += 32) {
    __syncthreads();
    gload16(Ab + (size_t)(bm0 + srow)      * D_ + k0 + scol, AsB + ldsOff);
    gload16(Ab + (size_t)(bm0 + 64 + srow) * D_ + k0 + scol, AsB + 4096 + ldsOff);
    gload16(Bb + (size_t)(bn0 + srow)      * D_ + k0 + scol, BsB + ldsOff);
    gload16(Bb + (size_t)(bn0 + 64 + srow) * D_ + k0 + scol, BsB + 4096 + ldsOff);
    __syncthreads();

    const int lrow = lane & 15, lk = (lane >> 4) * 8;
    bf16x8 af[4], bfr[4];
#pragma unroll
    for (int mi = 0; mi < 4; ++mi)
      af[mi] = *(const bf16x8*)((const char*)As + ((wr * 64 + mi * 16 + lrow) * 32 + lk) * 2);
#pragma unroll
    for (int ni = 0; ni < 4; ++ni)
      bfr[ni] = *(const bf16x8*)((const char*)Bs + ((wc * 64 + ni * 16 + lrow) * 32 + lk) * 2);
#pragma unroll
    for (int mi = 0; mi < 4; ++mi)
#pragma unroll
      for (int ni = 0; ni < 4; ++ni)
        acc[mi][ni] = __builtin_amdgcn_mfma_f32_16x16x32_bf16(af[mi], bfr[ni], acc[mi][ni], 0, 0, 0);
  }

  const int orow = (lane >> 4) * 4, ocol = lane & 15;
#pragma unroll
  for (int mi = 0; mi < 4; ++mi)
#pragma unroll
    for (int ni = 0; ni < 4; ++ni) {
      const int row = bm0 + wr * 64 + mi * 16 + orow;
      const int col = bn0 + wc * 64 + ni * 16 + ocol;
#pragma unroll
      for (int r = 0; r < 4; ++r)
        Gb[(size_t)(row + r) * N_ + col] = __float2half(acc[mi][ni][r]);
    }
}

// ---------------------------------------------------------------------------
// Fused streaming pass, slice-per-wave layout. 768 blocks, mat = bid % 3:
//   mat 0 (Gxy): row-LSE -> f_ba (slot 0); per-column partials -> colPart
//   mat 1 (Gxx): row-LSE -> f_aa (slot 2)
//   mat 2 (Gyy): row-LSE -> g_bb (slot 3)
// Block = (mat, b, stripe of 32 rows). Wave w owns cols [w*512, w*512+512);
// lane owns 8 cols -> hh[8], colm[8], cols[8] (24 VGPR state, vs 96 in the
// R3/R4 layout which capped occupancy at 2 blocks/CU and ran 40 us/pass).
// Row LSE: per-wave (m,s) partials in 1 KB LDS, merged by wave 0 at the end.
// MODE 0: init write. MODE 1: damped 0.5(old+new). MODE 2: loss accumulate.
// ---------------------------------------------------------------------------
#define L2E_ 1.44269504088896f
#define LN2_ 0.69314718055995f

template <int MODE>
__global__ __launch_bounds__(256) void sink_stream(
    const __half* __restrict__ Gxy, const __half* __restrict__ Gxx,
    const __half* __restrict__ Gyy,
    const float* __restrict__ potOld, float* __restrict__ potNew,
    float2* __restrict__ colPart, float eps, float* __restrict__ out) {
  __shared__ float2 part[4][32];   // [wave][row] row-slice partials

  const int bid = blockIdx.x;
  const int mat = bid % 3;
  const int rem = bid / 3;
  const int b = rem >> 6, stripe = rem & 63;
  const int lane = threadIdx.x & 63, wave = threadIdx.x >> 6;
  const int c0 = wave * 512 + lane * 8;     // first owned column

  const float inv_eps = 1.0f / eps;
  const float ieL  = inv_eps * L2E_;
  const float hbL  = (-7.62461898616f - inv_eps) * L2E_;  // (-log 2048 - 1/eps)*log2e
  const float negEpsLn2 = -eps * LN2_;

  const __half* G = (mat == 0 ? Gxy : mat == 1 ? Gxx : Gyy) + (size_t)b * N_ * N_;
  const int hIdx = (mat == 0) ? 1 : (mat == 1) ? 2 : 3;
  const int oIdx = (mat == 0) ? 0 : hIdx;
  const float* potH = potOld + ((size_t)hIdx * B_ + b) * N_;
  const float* potR = potOld + ((size_t)0    * B_ + b) * N_;  // f_ba for col pass
  const float* potO = potOld + ((size_t)oIdx * B_ + b) * N_;
  float*       potW = potNew + ((size_t)oIdx * B_ + b) * N_;

  // h for the 8 owned columns (log2 domain)
  float hh[8];
  if constexpr (MODE == 0) {
#pragma unroll
    for (int e = 0; e < 8; ++e) hh[e] = hbL;
  } else {
    const float4 a = *(const float4*)(potH + c0);
    const float4 c = *(const float4*)(potH + c0 + 4);
    hh[0] = fmaf(a.x, ieL, hbL); hh[1] = fmaf(a.y, ieL, hbL);
    hh[2] = fmaf(a.z, ieL, hbL); hh[3] = fmaf(a.w, ieL, hbL);
    hh[4] = fmaf(c.x, ieL, hbL); hh[5] = fmaf(c.y, ieL, hbL);
    hh[6] = fmaf(c.z, ieL, hbL); hh[7] = fmaf(c.w, ieL, hbL);
  }

  // online column accumulators (mat 0 only)
  float colm[8], cols_[8];
#pragma unroll
  for (int e = 0; e < 8; ++e) { colm[e] = -3.0e38f; cols_[e] = 0.0f; }

  const int rbase = stripe * 32;
  const __half* gbase = G + (size_t)rbase * N_ + c0;

  half8 A0, A1, P0, P1;
  A0 = *(const half8*)(gbase);
  A1 = *(const half8*)(gbase + N_);

#pragma unroll 1
  for (int it = 0; it < 16; ++it) {
    if (it < 15) {  // prefetch next row pair
      const __half* gp = gbase + (size_t)(it * 2 + 2) * N_;
      P0 = *(const half8*)(gp);
      P1 = *(const half8*)(gp + N_);
    }

    const int r0 = rbase + it * 2;
    float hr0 = hbL, hr1 = hbL;
    if (mat == 0 && MODE != 0) {
      hr0 = fmaf(potR[r0],     ieL, hbL);
      hr1 = fmaf(potR[r0 + 1], ieL, hbL);
    }

    // t = G/eps + h_col (log2 domain); row max over the slice
    float t0[8], t1[8];
    float mx0 = -3.0e38f, mx1 = -3.0e38f;
#pragma unroll
    for (int e = 0; e < 8; ++e) {
      t0[e] = fmaf((float)A0[e], ieL, hh[e]);
      t1[e] = fmaf((float)A1[e], ieL, hh[e]);
      mx0 = fmaxf(mx0, t0[e]);
      mx1 = fmaxf(mx1, t1[e]);
    }
#pragma unroll
    for (int off = 1; off < 64; off <<= 1) {
      mx0 = fmaxf(mx0, __shfl_xor(mx0, off));
      mx1 = fmaxf(mx1, __shfl_xor(mx1, off));
    }

    float sm0 = 0.0f, sm1 = 0.0f;
#pragma unroll
    for (int e = 0; e < 8; ++e) {
      sm0 += fexp2(t0[e] - mx0);
      sm1 += fexp2(t1[e] - mx1);
    }
#pragma unroll
    for (int off = 1; off < 64; off <<= 1) {
      sm0 += __shfl_xor(sm0, off);
      sm1 += __shfl_xor(sm1, off);
    }
    if (lane == 0) {
      part[wave][it * 2]     = make_float2(mx0, sm0);
      part[wave][it * 2 + 1] = make_float2(mx1, sm1);
    }

    // online column update (both rows at once): s = G/eps + h_row
    if (mat == 0) {
      const float d0 = hr0, d1 = hr1;
#pragma unroll
      for (int e = 0; e < 8; ++e) {
        const float s0 = t0[e] - hh[e] + d0;
        const float s1 = t1[e] - hh[e] + d1;
        const float nm = fmaxf(colm[e], fmaxf(s0, s1));
        const float add = fexp2(s0 - nm) + fexp2(s1 - nm);
        cols_[e] = fmaf(cols_[e], fexp2(colm[e] - nm), add);
        colm[e] = nm;
      }
    }

    A0 = P0; A1 = P1;
  }

  // column partial writeout (natural column order, fully coalesced)
  if (mat == 0) {
    float2* cp = colPart + ((size_t)(b * 64 + stripe) * 2048 + c0);
#pragma unroll
    for (int e = 0; e < 8; ++e) cp[e] = make_float2(colm[e], cols_[e]);
  }

  __syncthreads();

  // wave 0 merges the 4 slice-partials per row and writes the row potential
  float vfin = 0.0f;
  if (wave == 0 && lane < 32) {
    float2 q = part[0][lane];
    float m = q.x, s = q.y;
#pragma unroll
    for (int w = 1; w < 4; ++w) {
      const float2 q2 = part[w][lane];
      const float nm = fmaxf(m, q2.x);
      s = fmaf(s, fexp2(m - nm), q2.y * fexp2(q2.x - nm));
      m = nm;
    }
    const float v = negEpsLn2 * (m + flog2(s));
    const int r = rbase + lane;
    if constexpr (MODE == 0) {
      potW[r] = v;
    } else if constexpr (MODE == 1) {
      potW[r] = 0.5f * (potO[r] + v);
    } else {
      vfin = v;
    }
  }

  if constexpr (MODE == 2) {
#pragma unroll
    for (int off = 1; off < 64; off <<= 1) vfin += __shfl_xor(vfin, off);
    if (threadIdx.x == 0) {
      const float sign = (mat == 0) ? 1.0f : -1.0f;
      atomicAdd(out, sign * vfin * (1.0f / (2048.0f * B_)));
    }
  }
}

// ---------------------------------------------------------------------------
// Merge column partials across the 64 row-stripes -> g_ab (slot 1).
// 128 blocks x 256. Block = 64 consecutive global columns; wave w merges
// stripes [w*16, w*16+16) -> LDS -> wave 0 finalizes. All accesses coalesced.
// ---------------------------------------------------------------------------
template <int MODE>
__global__ __launch_bounds__(256) void sink_merge(
    const float2* __restrict__ colPart, const float* __restrict__ potOld,
    float* __restrict__ potNew, float eps, float* __restrict__ out) {
  __shared__ float2 mp[3][64];
  const int lane = threadIdx.x & 63, sub = threadIdx.x >> 6;
  const int colg = blockIdx.x * 64 + lane;          // 0..8191
  const int b = colg >> 11, col = colg & 2047;
  const float negEpsLn2 = -eps * LN2_;

  float m = -3.0e38f, s = 0.0f;
  const float2* cp = colPart + ((size_t)(b * 64 + sub * 16)) * 2048 + col;
#pragma unroll
  for (int st = 0; st < 16; ++st) {
    const float2 P = cp[(size_t)st * 2048];
    const float nm = fmaxf(m, P.x);
    s = fmaf(s, fexp2(m - nm), P.y * fexp2(P.x - nm));
    m = nm;
  }
  if (sub != 0) mp[sub - 1][lane] = make_float2(m, s);
  __syncthreads();

  float vfin = 0.0f;
  if (sub == 0) {
#pragma unroll
    for (int w = 0; w < 3; ++w) {
      const float2 q = mp[w][lane];
      const float nm = fmaxf(m, q.x);
      s = fmaf(s, fexp2(m - nm), q.y * fexp2(q.x - nm));
      m = nm;
    }
    const float v = negEpsLn2 * (m + flog2(s));
    if constexpr (MODE == 0) {
      potNew[((size_t)1 * B_ + b) * N_ + col] = v;
    } else if constexpr (MODE == 1) {
      potNew[((size_t)1 * B_ + b) * N_ + col] =
          0.5f * (potOld[((size_t)1 * B_ + b) * N_ + col] + v);
    } else {
      vfin = v;
    }
  }

  if constexpr (MODE == 2) {
#pragma unroll
    for (int off = 1; off < 64; off <<= 1) vfin += __shfl_xor(vfin, off);
    __shared__ float red[4];
    if ((threadIdx.x & 63) == 0) red[sub] = vfin;
    __syncthreads();
    if (threadIdx.x == 0)
      atomicAdd(out, (red[0] + red[1] + red[2] + red[3]) * (1.0f / (2048.0f * B_)));
  }
}

// ---------------------------------------------------------------------------
extern "C" void kernel_launch(void* const* d_in, const int* in_sizes, int n_in,
                              void* d_out, int out_size, void* d_ws, size_t ws_size,
                              hipStream_t stream) {
  const float* E_p = (const float*)d_in[0];
  const float* E_t = (const float*)d_in[1];
  float* out = (float*)d_out;
  char* ws = (char*)d_ws;

  size_t off = 0;
  auto alloc = [&](size_t bytes) {
    void* p = ws + off;
    off += (bytes + 255) & ~(size_t)255;
    return p;
  };
  __hip_bfloat16* Xb = (__hip_bfloat16*)alloc((size_t)B_ * N_ * D_ * 2);
  __hip_bfloat16* Yb = (__hip_bfloat16*)alloc((size_t)B_ * N_ * D_ * 2);
  __half* Gxy = (__half*)alloc((size_t)B_ * N_ * N_ * 2);
  __half* Gxx = (__half*)alloc((size_t)B_ * N_ * N_ * 2);
  __half* Gyy = (__half*)alloc((size_t)B_ * N_ * N_ * 2);
  float* potA = (float*)alloc((size_t)4 * B_ * N_ * 4);
  float* potB = (float*)alloc((size_t)4 * B_ * N_ * 4);
  float2* colPart = (float2*)alloc((size_t)B_ * 64 * 2048 * 8);

  norm_kernel<<<B_ * N_, 256, 0, stream>>>(E_p, Xb);
  norm_kernel<<<B_ * N_, 256, 0, stream>>>(E_t, Yb);

  dim3 gg(16, 16, 12);
  gram_gemm<<<gg, 256, 0, stream>>>(Xb, Yb, Gxy, Gxx, Gyy);

  // epsilon schedule (numpy arange semantics, double precision)
  float epsl[48];
  int ne = 0;
  epsl[ne++] = 4.0f;
  {
    const double lstart = 2.0 * log(2.0);
    const double lstop  = 2.0 * log(0.05);
    const double lstep  = 2.0 * log(0.9);
    for (int k = 0;; ++k) {
      const double v = lstart + k * lstep;
      if (!(v > lstop)) break;
      epsl[ne++] = (float)exp(v);
    }
  }
  epsl[ne++] = 0.0025f;

  (void)hipMemsetAsync(d_out, 0, sizeof(float), stream);

  // init at eps0
  sink_stream<0><<<768, 256, 0, stream>>>(Gxy, Gxx, Gyy, potA, potA, colPart,
                                          epsl[0], nullptr);
  sink_merge<0><<<128, 256, 0, stream>>>(colPart, potA, potA, epsl[0], nullptr);

  // damped scan over the schedule
  float* cur = potA;
  float* nxt = potB;
  for (int i = 0; i < ne; ++i) {
    sink_stream<1><<<768, 256, 0, stream>>>(Gxy, Gxx, Gyy, cur, nxt, colPart,
                                            epsl[i], nullptr);
    sink_merge<1><<<128, 256, 0, stream>>>(colPart, cur, nxt, epsl[i], nullptr);
    float* tmp = cur; cur = nxt; nxt = tmp;
  }

  // final extrapolation + loss
  sink_stream<2><<<768, 256, 0, stream>>>(Gxy, Gxx, Gyy, cur, cur, colPart,
                                          epsl[ne - 1], out);
  sink_merge<2><<<128, 256, 0, stream>>>(colPart, cur, cur, epsl[ne - 1], out);
}